// Round 5
// baseline (801.845 us; speedup 1.0000x reference)
//
#include <hip/hip_runtime.h>

typedef unsigned long long u64;
typedef unsigned int u32;

#define NB 8
#define NPIX 65536   // 256*256

// monotone float->uint encoding (order-preserving for all reals)
__device__ __forceinline__ u32 fsort(float f){
  u32 u = __float_as_uint(f);
  return (u & 0x80000000u) ? ~u : (u | 0x80000000u);
}
__device__ __forceinline__ float funsort(u32 s){
  u32 u = (s & 0x80000000u) ? (s ^ 0x80000000u) : ~s;
  return __uint_as_float(u);
}

// ---------------- init: zero packed best-map, init use map + pos sentinels ----
__global__ void init_kernel(u64* __restrict__ packed, float* __restrict__ u,
                            int* __restrict__ pxy){
  int idx = blockIdx.x * 256 + threadIdx.x;
  if (idx < NB * NPIX){
    packed[idx] = 0ull;
    int p = idx & (NPIX - 1);
    int x = p >> 8, y = p & 255;
    u[idx] = (x >= 16 && x < 240 && y >= 16 && y < 240) ? 1.0f : 0.0f;
  }
  if (idx < 2 * NB) pxy[idx] = -100000;  // sentinel: first iter tmap==1 everywhere
}

// ---------------- conv + per-pixel max over d (fused) -----------------------
// conv[b,d,x,y] = sum_{fy,fx} input[b,(x+fy-16)%256,(y+fx-16)%256] * filt[d,fy,fx]
// Block: 16-row x 256-col output stripe for one b, 16 d's.
// Thread: 1 row x 16 cols; per fy reads a 48-float window (12 x b128) from a
// full-width 48x256 LDS halo, XOR-swizzled at float4-block granularity.
// R5: fy-pipelined — window double-buffered (wA/wB), loads for fy+1 issued
// before the FMA block of fy, so the mandatory lgkmcnt(0) drain (mixed
// SMEM filter + DS window on one counter) overlaps the other wave's compute.
__global__ __launch_bounds__(256) void conv_best_kernel(
    const float* __restrict__ input, const float* __restrict__ filt,
    const float* __restrict__ prior, u64* __restrict__ packed)
{
  __shared__ float sin_[48 * 256];
  const int tile = blockIdx.x;        // 0..15 (output rows tile*16..tile*16+15)
  const int b    = blockIdx.y;        // 0..7
  const int g    = blockIdx.z;        // 0..3 (16 d's each)
  const int tX = tile << 4;
  const int tid = threadIdx.x;

  const float* inb = input + b * NPIX;
  // stage 48 full rows (input rows tX-16 .. tX+31 mod 256), swizzled
  for (int k = tid; k < 48 * 64; k += 256){
    int row = k >> 6;                  // 0..47
    int B   = k & 63;                  // 16B block within row
    int gx  = (tX - 16 + row) & 255;
    float4 v = *(const float4*)(inb + (gx << 8) + (B << 2));
    int Bs = B ^ ((B >> 3) & 7) ^ (row & 7);
    *(float4*)(sin_ + row * 256 + (Bs << 2)) = v;
  }
  __syncthreads();

  const int ty = tid >> 4;            // 0..15 output row within stripe
  const int tx = tid & 15;            // 0..15 -> cols tx*16..tx*16+15

  // precompute swizzle-prefix for the 12 window blocks (fy-independent)
  int pre[12];
  #pragma unroll
  for (int q = 0; q < 12; ++q){
    int Bq = ((tx << 2) + q + 60) & 63;   // block of col tx*16-16+4q (mod 256)
    pre[q] = Bq ^ ((Bq >> 3) & 7);
  }

  float bv[16];
  int   bd[16];
  #pragma unroll
  for (int i = 0; i < 16; ++i){ bv[i] = -3e38f; bd[i] = 0; }

#define LOADW(W, ROW)                                                   \
  {                                                                     \
    const int row_ = (ROW);                                             \
    const int rm_ = row_ & 7;                                           \
    const float* base_ = sin_ + row_ * 256;                             \
    _Pragma("unroll")                                                   \
    for (int q = 0; q < 12; ++q){                                       \
      float4 v_ = *(const float4*)(base_ + ((pre[q] ^ rm_) << 2));      \
      W[4*q+0]=v_.x; W[4*q+1]=v_.y; W[4*q+2]=v_.z; W[4*q+3]=v_.w;       \
    }                                                                   \
  }

#define FMAROW(ACC, W, FR)                                              \
  {                                                                     \
    const float* fr_ = (FR);   /* wave-uniform -> s_load */             \
    _Pragma("unroll")                                                   \
    for (int fx = 0; fx < 33; ++fx){                                    \
      const float fv_ = fr_[fx];                                        \
      _Pragma("unroll")                                                 \
      for (int c = 0; c < 16; ++c)                                      \
        ACC[c] = fmaf(fv_, W[c + fx], ACC[c]);                          \
    }                                                                   \
  }

  #pragma unroll 1
  for (int dl = 0; dl < 16; ++dl){
    const int d = (g << 4) + dl;
    const float* __restrict__ frow = filt + d * 1089;

    float acc[16] = {};
    float wA[48], wB[48];

    LOADW(wA, ty)                       // row for fy=0

    #pragma unroll 1
    for (int fy = 0; fy < 32; fy += 2){
      LOADW(wB, ty + fy + 1)            // prefetch fy+1 window
      FMAROW(acc, wA, frow + fy * 33)   // consume fy
      LOADW(wA, ty + fy + 2)            // prefetch fy+2 window
      FMAROW(acc, wB, frow + fy * 33 + 33) // consume fy+1
    }
    FMAROW(acc, wA, frow + 32 * 33)     // fy=32 (loaded in last iteration)

    const float pr = prior[d];
    #pragma unroll
    for (int c = 0; c < 16; ++c){
      float v = acc[c] * pr;
      if (v > bv[c]){ bv[c] = v; bd[c] = d; }   // ascending d: strict > keeps smallest d
    }
  }
#undef LOADW
#undef FMAROW

  u64* pb = packed + b * NPIX;
  const int x = tX + ty;
  #pragma unroll
  for (int c = 0; c < 16; ++c){
    int y = (tx << 4) + c;
    u64 key = ((u64)fsort(bv[c]) << 32) | (u64)(63 - bd[c]); // tie -> smaller d
    atomicMax(&pb[(x << 8) + y], key);
  }
}

// ---------------- per-iteration: apply deadzone, scan for argmax + umax -----
__global__ __launch_bounds__(256) void scan_kernel(
    const u64* __restrict__ packed, float* __restrict__ u, const int* __restrict__ pxy,
    float* __restrict__ smax, int* __restrict__ sidx, float* __restrict__ umax)
{
  const int b   = blockIdx.y;
  const int blk = blockIdx.x;          // 0..31
  const int tid = threadIdx.x;
  const int px = pxy[2 * b], py = pxy[2 * b + 1];
  const int base = blk * 2048;

  float lmax = -3e38f; int lidx = 0; float lu = 0.f;
  for (int k = tid; k < 2048; k += 256){
    const int p = base + k;
    const int idx = b * NPIX + p;
    float uu = u[idx];
    int x = p >> 8, y = p & 255;
    float dx = (float)(x - px), dy = (float)(y - py);
    float d2 = dx * dx + dy * dy;
    float t = 1.f - __expf(d2 * -0.03125f);     // 1/(2*sigma^2), sigma=4
    if (d2 <= 16.f) t = 0.f;                    // hard cutout r=4
    uu *= t;
    u[idx] = uu;
    float bvv = funsort((u32)(packed[idx] >> 32));
    float s = bvv * uu;
    if (s > lmax || (s == lmax && p < lidx)){ lmax = s; lidx = p; }
    if (uu > lu) lu = uu;
  }
  __shared__ float rmax[256]; __shared__ int rid[256]; __shared__ float rum[256];
  rmax[tid] = lmax; rid[tid] = lidx; rum[tid] = lu;
  __syncthreads();
  for (int s = 128; s > 0; s >>= 1){
    if (tid < s){
      float v2 = rmax[tid + s]; int i2 = rid[tid + s];
      if (v2 > rmax[tid] || (v2 == rmax[tid] && i2 < rid[tid])){ rmax[tid] = v2; rid[tid] = i2; }
      if (rum[tid + s] > rum[tid]) rum[tid] = rum[tid + s];
    }
    __syncthreads();
  }
  if (tid == 0){
    smax[b * 32 + blk] = rmax[0];
    sidx[b * 32 + blk] = rid[0];
    umax[b * 32 + blk] = rum[0];
  }
}

// ---------------- finalize iteration: reduce 32 partials, emit outputs ------
__global__ void final_kernel(const u64* __restrict__ packed, const float* __restrict__ prior,
    const float* __restrict__ smax, const int* __restrict__ sidx, const float* __restrict__ umax,
    int* __restrict__ pxy, float* __restrict__ out, int t)
{
  const int b = blockIdx.x;
  const int lane = threadIdx.x;   // 64 threads, entries in lanes 0..31
  float v = -3e38f; int id = 0x7fffffff; float um = 0.f;
  if (lane < 32){ v = smax[b * 32 + lane]; id = sidx[b * 32 + lane]; um = umax[b * 32 + lane]; }
  #pragma unroll
  for (int off = 32; off > 0; off >>= 1){
    float v2 = __shfl_down(v, off);
    int   i2 = __shfl_down(id, off);
    float u2 = __shfl_down(um, off);
    if (v2 > v || (v2 == v && i2 < id)){ v = v2; id = i2; }
    if (u2 > um) um = u2;
  }
  if (lane == 0){
    int x = id >> 8, y = id & 255;
    u64 key = packed[b * NPIX + id];
    int d = 63 - (int)(key & 63ull);
    float bvv = funsort((u32)(key >> 32));
    out[b * 30 + t * 3 + 0] = (float)d;     // position_found [B,10,3]
    out[b * 30 + t * 3 + 1] = (float)x;
    out[b * 30 + t * 3 + 2] = (float)y;
    out[240 + b * 20 + t * 2 + 0] = v / um;        // ov0: max incl. prior (normalized u)
    out[240 + b * 20 + t * 2 + 1] = bvv / prior[d];// ov1: raw conv value
    pxy[2 * b] = x; pxy[2 * b + 1] = y;
  }
}

extern "C" void kernel_launch(void* const* d_in, const int* in_sizes, int n_in,
                              void* d_out, int out_size, void* d_ws, size_t ws_size,
                              hipStream_t stream)
{
  const float* input = (const float*)d_in[0];
  const float* filt  = (const float*)d_in[1];
  // d_in[2] (dictionary) is unused by the reference
  const float* prior = (const float*)d_in[3];
  float* out = (float*)d_out;

  char* ws = (char*)d_ws;
  u64*   packed = (u64*)(ws);                  // 8*65536*8 = 4,194,304 B
  float* u      = (float*)(ws + 4194304);      // 2,097,152 B
  float* smax   = (float*)(ws + 6291456);      // 1024 B
  int*   sidx   = (int*)  (ws + 6292480);      // 1024 B
  float* umax   = (float*)(ws + 6293504);      // 1024 B
  int*   pxy    = (int*)  (ws + 6294528);      // 64 B

  init_kernel<<<2048, 256, 0, stream>>>(packed, u, pxy);
  conv_best_kernel<<<dim3(16, NB, 4), 256, 0, stream>>>(input, filt, prior, packed);
  for (int t = 0; t < 10; ++t){
    scan_kernel<<<dim3(32, NB), 256, 0, stream>>>(packed, u, pxy, smax, sidx, umax);
    final_kernel<<<NB, 64, 0, stream>>>(packed, prior, smax, sidx, umax, pxy, out, t);
  }
}

// Round 7
// 367.242 us; speedup vs baseline: 2.1834x; 2.1834x over previous
//
#include <hip/hip_runtime.h>

typedef unsigned long long u64;
typedef unsigned int u32;
typedef unsigned short ushort_t;

using f32x16 = __attribute__((ext_vector_type(16))) float;
using f32x4  = __attribute__((ext_vector_type(4))) float;
using short8 = __attribute__((ext_vector_type(8))) short;

#define NB 8
#define NPIX 65536
#define CAND_CAP 65536

// monotone float<->uint order-preserving encoding
__device__ __forceinline__ u32 fsort(float f){
  u32 u = __float_as_uint(f);
  return (u & 0x80000000u) ? ~u : (u | 0x80000000u);
}
__device__ __forceinline__ float funsort(u32 s){
  u32 u = (s & 0x80000000u) ? (s ^ 0x80000000u) : ~s;
  return __uint_as_float(u);
}
// round-to-nearest-even f32 -> bf16 bits
__device__ __forceinline__ u32 rneb(float f){
  u32 x = __float_as_uint(f);
  return (x + 0x7fffu + ((x >> 16) & 1u)) >> 16;
}
__device__ __forceinline__ float bf2f(u32 h){ return __uint_as_float(h << 16); }

// ---------------- prep: filter fragments (bf16 hi/lo), corner f32, priorR ----
// A-frag (main): [fy 0..32][kc 0..1][dt 0..1][lane][j 0..7]
//   d = dt*32 + (lane&31); fx = 16*kc + 8*(lane>>5) + j
// A-frag (column): [kc][dt][lane][j]: fy = 16*kc + 8*(lane>>5) + j, fx = 32 (hi only)
// fcorner/priorR: [dt][lane][reg]: d = dt*32 + (reg&3) + 8*(reg>>2) + 4*(lane>>5)
__global__ __launch_bounds__(256) void prep_kernel(
    const float* __restrict__ filt, const float* __restrict__ prior,
    ushort_t* __restrict__ afh, ushort_t* __restrict__ afl,
    ushort_t* __restrict__ acolh, float* __restrict__ fcorner,
    float* __restrict__ priorR)
{
  int t = blockIdx.x * 256 + threadIdx.x;   // 16384 threads
  for (int i = t; i < 67584; i += 16384){
    int j = i & 7; int fidx = i >> 3; int lane = fidx & 63; int rest = fidx >> 6;
    int dt = rest & 1; int kc = (rest >> 1) & 1; int fy = rest >> 2;
    int d = dt * 32 + (lane & 31);
    int fx = 16 * kc + 8 * (lane >> 5) + j;
    float v = filt[d * 1089 + fy * 33 + fx];
    u32 hb = rneb(v);
    afh[i] = (ushort_t)hb;
    afl[i] = (ushort_t)rneb(v - bf2f(hb));
  }
  for (int i = t; i < 2048; i += 16384){
    int j = i & 7; int fidx = i >> 3; int lane = fidx & 63; int rest = fidx >> 6;
    int dt = rest & 1; int kc = rest >> 1;
    int d = dt * 32 + (lane & 31);
    int fy = 16 * kc + 8 * (lane >> 5) + j;
    acolh[i] = (ushort_t)rneb(filt[d * 1089 + fy * 33 + 32]);
  }
  for (int i = t; i < 2048; i += 16384){
    int reg = i & 15; int rest = i >> 4; int lane = rest & 63; int dt = rest >> 6;
    int d = dt * 32 + (reg & 3) + 8 * (reg >> 2) + 4 * (lane >> 5);
    fcorner[i] = filt[d * 1089 + 1088];
    priorR[i] = prior[d];
  }
}

// ---------------- init ------------------------------------------------------
__global__ void init_kernel(u64* __restrict__ packed, float* __restrict__ u,
                            int* __restrict__ pxy, u32* __restrict__ mmax,
                            u32* __restrict__ ncand){
  int idx = blockIdx.x * 256 + threadIdx.x;
  if (idx < NB * NPIX){
    packed[idx] = 0ull;
    int p = idx & (NPIX - 1);
    int x = p >> 8, y = p & 255;
    u[idx] = (x >= 16 && x < 240 && y >= 16 && y < 240) ? 1.0f : 0.0f;
  }
  if (idx < 2 * NB) pxy[idx] = -100000;
  if (idx < 8) mmax[idx] = 0u;
  if (idx == 0) *ncand = 0u;
}

// ---------------- conv via MFMA (split bf16) --------------------------------
__device__ __forceinline__ u32 funnel(u32 hi, u32 lo, int sh){
  return (u32)((((u64)hi << 32) | (u64)lo) >> sh);
}
template<int J>
__device__ __forceinline__ short8 extractf(uint4 P0, uint4 P1, int sh){
  u32 W[8] = {P0.x, P0.y, P0.z, P0.w, P1.x, P1.y, P1.z, P1.w};
  uint4 t;
  t.x = funnel(W[J + 1], W[J + 0], sh);
  t.y = funnel(W[J + 2], W[J + 1], sh);
  t.z = funnel(W[J + 3], W[J + 2], sh);
  t.w = funnel(W[J + 4], W[J + 3], sh);
  return __builtin_bit_cast(short8, t);
}
__device__ __forceinline__ f32x16 zero16(){
  f32x16 v;
  #pragma unroll
  for (int i = 0; i < 16; ++i) v[i] = 0.f;
  return v;
}

// LDS: hi rows [40][256] bf16 at byte 0 (row stride 512B), lo at byte 20480.
template<int J>
__device__ __forceinline__ void conv_body(
    const char* ldsc, const ushort_t* lds16, int w, int l, int tX,
    const short8* __restrict__ afh8, const short8* __restrict__ afl8,
    const short8* __restrict__ acol8, const f32x4* __restrict__ fcp,
    const f32x4* __restrict__ prp, u64* __restrict__ pb, int sh)
{
  const int c = l & 31, h = l >> 5;
  const int y0 = w;                 // 0..7; pixels y = y0 + 8c
  int cob0[2], cob1[2];
  #pragma unroll
  for (int kc = 0; kc < 2; ++kc){
    int yp = (y0 + 8 * c + 16 * kc + 8 * h - 16) & 255;
    int b0 = yp >> 3, b1 = (b0 + 1) & 31;
    cob0[kc] = b0 * 16; cob1[kc] = b1 * 16;
  }
  const int cc = (y0 + 8 * c + 16) & 255;   // column-pass / corner col

  for (int g0 = 0; g0 < 4; ++g0){
    const int r0 = g0 * 2;                  // rows r0, r0+1
    f32x16 acc[2][2];                       // [nr][dt]
    #pragma unroll
    for (int nr = 0; nr < 2; ++nr)
      #pragma unroll
      for (int dt = 0; dt < 2; ++dt) acc[nr][dt] = zero16();

    int aH0[2], aH1[2];
    #pragma unroll
    for (int kc = 0; kc < 2; ++kc){ aH0[kc] = r0 * 512 + cob0[kc]; aH1[kc] = r0 * 512 + cob1[kc]; }

    short8 a0h[2][2], a0l[2][2], a1h[2][2], a1l[2][2];
    #pragma unroll
    for (int kc = 0; kc < 2; ++kc)
      #pragma unroll
      for (int dt = 0; dt < 2; ++dt){
        a0h[kc][dt] = afh8[((0 * 2 + kc) * 2 + dt) * 64 + l];
        a0l[kc][dt] = afl8[((0 * 2 + kc) * 2 + dt) * 64 + l];
      }

#define CPH(AH, AL, NH, NL, FYP, DOPF)                                        \
    {                                                                         \
      if (DOPF){                                                              \
        _Pragma("unroll")                                                     \
        for (int kc = 0; kc < 2; ++kc)                                        \
          _Pragma("unroll")                                                   \
          for (int dt = 0; dt < 2; ++dt){                                     \
            NH[kc][dt] = afh8[(((FYP) * 2 + kc) * 2 + dt) * 64 + l];          \
            NL[kc][dt] = afl8[(((FYP) * 2 + kc) * 2 + dt) * 64 + l];          \
          }                                                                   \
      }                                                                       \
      short8 Bh[2][2], Bl[2][2];                                              \
      _Pragma("unroll")                                                       \
      for (int nr = 0; nr < 2; ++nr)                                          \
        _Pragma("unroll")                                                     \
        for (int kc = 0; kc < 2; ++kc){                                       \
          uint4 p0 = *(const uint4*)(ldsc + aH0[kc] + nr * 512);              \
          uint4 p1 = *(const uint4*)(ldsc + aH1[kc] + nr * 512);              \
          uint4 q0 = *(const uint4*)(ldsc + aH0[kc] + nr * 512 + 20480);      \
          uint4 q1 = *(const uint4*)(ldsc + aH1[kc] + nr * 512 + 20480);      \
          Bh[nr][kc] = extractf<J>(p0, p1, sh);                               \
          Bl[nr][kc] = extractf<J>(q0, q1, sh);                               \
        }                                                                     \
      _Pragma("unroll")                                                       \
      for (int nr = 0; nr < 2; ++nr)                                          \
        _Pragma("unroll")                                                     \
        for (int kc = 0; kc < 2; ++kc)                                        \
          _Pragma("unroll")                                                   \
          for (int dt = 0; dt < 2; ++dt){                                     \
            acc[nr][dt] = __builtin_amdgcn_mfma_f32_32x32x16_bf16(            \
                AH[kc][dt], Bh[nr][kc], acc[nr][dt], 0, 0, 0);                \
            acc[nr][dt] = __builtin_amdgcn_mfma_f32_32x32x16_bf16(            \
                AH[kc][dt], Bl[nr][kc], acc[nr][dt], 0, 0, 0);                \
            acc[nr][dt] = __builtin_amdgcn_mfma_f32_32x32x16_bf16(            \
                AL[kc][dt], Bh[nr][kc], acc[nr][dt], 0, 0, 0);                \
          }                                                                   \
      _Pragma("unroll")                                                       \
      for (int kc = 0; kc < 2; ++kc){ aH0[kc] += 512; aH1[kc] += 512; }       \
    }

    #pragma unroll 1
    for (int fy2 = 0; fy2 < 32; fy2 += 2){
      CPH(a0h, a0l, a1h, a1l, fy2 + 1, true)
      CPH(a1h, a1l, a0h, a0l, fy2 + 2, true)   // fy2+2 <= 32
    }
    CPH(a0h, a0l, a1h, a1l, 0, false)          // fy = 32
#undef CPH

    // column pass: fx = 32, k = fy (0..31), hi-only
    #pragma unroll
    for (int nr = 0; nr < 2; ++nr){
      #pragma unroll
      for (int kc = 0; kc < 2; ++kc){
        int base = (r0 + nr + 16 * kc + 8 * h) * 512 + cc * 2;
        u32 v0 = *(const ushort_t*)(ldsc + base + 0 * 512);
        u32 v1 = *(const ushort_t*)(ldsc + base + 1 * 512);
        u32 v2 = *(const ushort_t*)(ldsc + base + 2 * 512);
        u32 v3 = *(const ushort_t*)(ldsc + base + 3 * 512);
        u32 v4 = *(const ushort_t*)(ldsc + base + 4 * 512);
        u32 v5 = *(const ushort_t*)(ldsc + base + 5 * 512);
        u32 v6 = *(const ushort_t*)(ldsc + base + 6 * 512);
        u32 v7 = *(const ushort_t*)(ldsc + base + 7 * 512);
        uint4 t;
        t.x = v0 | (v1 << 16); t.y = v2 | (v3 << 16);
        t.z = v4 | (v5 << 16); t.w = v6 | (v7 << 16);
        short8 Bc = __builtin_bit_cast(short8, t);
        #pragma unroll
        for (int dt = 0; dt < 2; ++dt)
          acc[nr][dt] = __builtin_amdgcn_mfma_f32_32x32x16_bf16(
              acol8[(kc * 2 + dt) * 64 + l], Bc, acc[nr][dt], 0, 0, 0);
      }
    }

    // corner (fy=32, fx=32) exact f32 + prior-scale + per-pixel best + store
    // NOTE (R6 bug): lanes l and l+32 hold the SAME output column (col=lane&31)
    // but complementary d-halves (row formula has +4*(lane>>5)). Must combine
    // across half-waves before storing, else the two lanes race on pb[...].
    #pragma unroll
    for (int nr = 0; nr < 2; ++nr){
      u32 hv = lds16[(r0 + nr + 32) * 256 + cc];
      u32 lv = lds16[10240 + (r0 + nr + 32) * 256 + cc];
      float cv = bf2f(hv) + bf2f(lv);
      float bv = -3e38f; int bd = 0;
      #pragma unroll
      for (int dt = 0; dt < 2; ++dt){
        #pragma unroll
        for (int q = 0; q < 4; ++q){
          f32x4 fc4 = fcp[(dt * 64 + l) * 4 + q];
          f32x4 pr4 = prp[(dt * 64 + l) * 4 + q];
          #pragma unroll
          for (int e = 0; e < 4; ++e){
            int reg = q * 4 + e;
            float s = (acc[nr][dt][reg] + fc4[e] * cv) * pr4[e];
            int d = dt * 32 + e + 8 * q + 4 * h;
            if (s > bv || (s == bv && d < bd)){ bv = s; bd = d; }
          }
        }
      }
      int x = tX + r0 + nr;
      int y = y0 + 8 * c;
      u64 key = ((u64)fsort(bv) << 32) | (u64)(63 - bd);
      u64 other = __shfl_xor(key, 32);     // combine the two d-halves
      if (other > key) key = other;
      if (h == 0) pb[(x << 8) | y] = key;  // single writer per pixel
    }
  }
}

__global__ __launch_bounds__(512) void conv_mfma(
    const float* __restrict__ input,
    const ushort_t* __restrict__ afh, const ushort_t* __restrict__ afl,
    const ushort_t* __restrict__ acolh, const float* __restrict__ fcorner,
    const float* __restrict__ priorR, u64* __restrict__ packed)
{
  __shared__ ushort_t lds[20480];          // hi [40][256], lo at +10240
  const int bS = blockIdx.x;               // stripe 0..31
  const int b  = blockIdx.y;
  const int tX = bS * 8;
  const int tid = threadIdx.x;

  const float* inb = input + b * NPIX;
  u32* ldsw = (u32*)lds;
  for (int k = tid; k < 2560; k += 512){   // 40 rows * 64 float4
    int r = k >> 6, c4 = k & 63;
    int gx = (tX - 16 + r) & 255;
    float4 v = *(const float4*)(inb + (gx << 8) + (c4 << 2));
    u32 h0 = rneb(v.x), h1 = rneb(v.y), h2 = rneb(v.z), h3 = rneb(v.w);
    u32 l0 = rneb(v.x - bf2f(h0)), l1 = rneb(v.y - bf2f(h1));
    u32 l2 = rneb(v.z - bf2f(h2)), l3 = rneb(v.w - bf2f(h3));
    int wi = r * 128 + c4 * 2;
    ldsw[wi]     = h0 | (h1 << 16);
    ldsw[wi + 1] = h2 | (h3 << 16);
    ldsw[5120 + wi]     = l0 | (l1 << 16);
    ldsw[5120 + wi + 1] = l2 | (l3 << 16);
  }
  __syncthreads();

  const int w = tid >> 6, l = tid & 63;
  u64* pb = packed + b * NPIX;
  const int sh = 16 * (w & 1);
  const char* ldsc = (const char*)lds;
  const short8* afh8 = (const short8*)afh;
  const short8* afl8 = (const short8*)afl;
  const short8* acol8 = (const short8*)acolh;
  const f32x4* fcp = (const f32x4*)fcorner;
  const f32x4* prp = (const f32x4*)priorR;

  switch ((w >> 1) & 3){
    case 0: conv_body<0>(ldsc, lds, w, l, tX, afh8, afl8, acol8, fcp, prp, pb, sh); break;
    case 1: conv_body<1>(ldsc, lds, w, l, tX, afh8, afl8, acol8, fcp, prp, pb, sh); break;
    case 2: conv_body<2>(ldsc, lds, w, l, tX, afh8, afl8, acol8, fcp, prp, pb, sh); break;
    default: conv_body<3>(ldsc, lds, w, l, tX, afh8, afl8, acol8, fcp, prp, pb, sh); break;
  }
}

// ---------------- per-batch approx max --------------------------------------
__global__ __launch_bounds__(256) void bmax_kernel(const u64* __restrict__ packed,
                                                   u32* __restrict__ mmax){
  const int b = blockIdx.y, blk = blockIdx.x, tid = threadIdx.x;
  u32 m = 0;
  for (int k = tid; k < 2048; k += 256)
    m = max(m, (u32)(packed[b * NPIX + blk * 2048 + k] >> 32));
  __shared__ u32 red[256];
  red[tid] = m; __syncthreads();
  for (int s = 128; s > 0; s >>= 1){
    if (tid < s) red[tid] = max(red[tid], red[tid + s]);
    __syncthreads();
  }
  if (tid == 0) atomicMax(&mmax[b], red[0]);
}

// ---------------- collect candidates within margin of max -------------------
__global__ __launch_bounds__(256) void collect_kernel(const u64* __restrict__ packed,
    const u32* __restrict__ mmax, u32* __restrict__ ncand, u32* __restrict__ cand){
  const int b = blockIdx.y, blk = blockIdx.x, tid = threadIdx.x;
  float M = funsort(mmax[b]);
  u32 tu = fsort(M - 44.0f);
  for (int k = tid; k < 2048; k += 256){
    int p = blk * 2048 + k;
    u32 v = (u32)(packed[b * NPIX + p] >> 32);
    if (v >= tu){
      u32 slot = atomicAdd(ncand, 1u);
      if (slot < CAND_CAP) cand[slot] = ((u32)b << 16) | (u32)p;
    }
  }
}

// ---------------- exact fp32 recompute for candidates, patch map ------------
__global__ __launch_bounds__(64) void rerank_kernel(
    const float* __restrict__ input, const float* __restrict__ filt,
    const float* __restrict__ prior, const u32* __restrict__ ncand,
    const u32* __restrict__ cand, u64* __restrict__ packed)
{
  const int lane = threadIdx.x;            // = d
  int n = (int)min(*ncand, (u32)CAND_CAP);
  const float* fb = filt + lane * 1089;
  float pv = prior[lane];
  for (int i = blockIdx.x; i < n; i += 1024){
    u32 v = cand[i];
    int b = v >> 16, p = v & 0xffff;
    int px = p >> 8, py = p & 255;
    int yc = py - 16;
    float s = 0.f;
    for (int fy = 0; fy < 33; ++fy){
      const float* ir = input + b * NPIX + (((px + fy - 16) & 255) << 8);
      const float* fr = fb + fy * 33;
      for (int fx = 0; fx < 33; ++fx)
        s = fmaf(fr[fx], ir[(yc + fx) & 255], s);
    }
    u64 key = ((u64)fsort(s * pv) << 32) | (u64)(63 - lane);
    #pragma unroll
    for (int off = 32; off; off >>= 1){
      u64 o = __shfl_down(key, off);
      if (o > key) key = o;
    }
    if (lane == 0) packed[b * NPIX + p] = key;
  }
}

// ---------------- greedy iteration: deadzone + argmax scan ------------------
__global__ __launch_bounds__(256) void scan_kernel(
    const u64* __restrict__ packed, float* __restrict__ u, const int* __restrict__ pxy,
    float* __restrict__ smax, int* __restrict__ sidx, float* __restrict__ umax)
{
  const int b   = blockIdx.y;
  const int blk = blockIdx.x;
  const int tid = threadIdx.x;
  const int px = pxy[2 * b], py = pxy[2 * b + 1];
  const int base = blk * 2048;

  float lmax = -3e38f; int lidx = 0; float lu = 0.f;
  for (int k = tid; k < 2048; k += 256){
    const int p = base + k;
    const int idx = b * NPIX + p;
    float uu = u[idx];
    int x = p >> 8, y = p & 255;
    float dx = (float)(x - px), dy = (float)(y - py);
    float d2 = dx * dx + dy * dy;
    float t = 1.f - __expf(d2 * -0.03125f);
    if (d2 <= 16.f) t = 0.f;
    uu *= t;
    u[idx] = uu;
    float bvv = funsort((u32)(packed[idx] >> 32));
    float s = bvv * uu;
    if (s > lmax || (s == lmax && p < lidx)){ lmax = s; lidx = p; }
    if (uu > lu) lu = uu;
  }
  __shared__ float rmax[256]; __shared__ int rid[256]; __shared__ float rum[256];
  rmax[tid] = lmax; rid[tid] = lidx; rum[tid] = lu;
  __syncthreads();
  for (int s = 128; s > 0; s >>= 1){
    if (tid < s){
      float v2 = rmax[tid + s]; int i2 = rid[tid + s];
      if (v2 > rmax[tid] || (v2 == rmax[tid] && i2 < rid[tid])){ rmax[tid] = v2; rid[tid] = i2; }
      if (rum[tid + s] > rum[tid]) rum[tid] = rum[tid + s];
    }
    __syncthreads();
  }
  if (tid == 0){
    smax[b * 32 + blk] = rmax[0];
    sidx[b * 32 + blk] = rid[0];
    umax[b * 32 + blk] = rum[0];
  }
}

__global__ void final_kernel(const u64* __restrict__ packed, const float* __restrict__ prior,
    const float* __restrict__ smax, const int* __restrict__ sidx, const float* __restrict__ umax,
    int* __restrict__ pxy, float* __restrict__ out, int t)
{
  const int b = blockIdx.x;
  const int lane = threadIdx.x;
  float v = -3e38f; int id = 0x7fffffff; float um = 0.f;
  if (lane < 32){ v = smax[b * 32 + lane]; id = sidx[b * 32 + lane]; um = umax[b * 32 + lane]; }
  #pragma unroll
  for (int off = 32; off > 0; off >>= 1){
    float v2 = __shfl_down(v, off);
    int   i2 = __shfl_down(id, off);
    float u2 = __shfl_down(um, off);
    if (v2 > v || (v2 == v && i2 < id)){ v = v2; id = i2; }
    if (u2 > um) um = u2;
  }
  if (lane == 0){
    int x = id >> 8, y = id & 255;
    u64 key = packed[b * NPIX + id];
    int d = 63 - (int)(key & 63ull);
    float bvv = funsort((u32)(key >> 32));
    out[b * 30 + t * 3 + 0] = (float)d;
    out[b * 30 + t * 3 + 1] = (float)x;
    out[b * 30 + t * 3 + 2] = (float)y;
    out[240 + b * 20 + t * 2 + 0] = v / um;
    out[240 + b * 20 + t * 2 + 1] = bvv / prior[d];
    pxy[2 * b] = x; pxy[2 * b + 1] = y;
  }
}

extern "C" void kernel_launch(void* const* d_in, const int* in_sizes, int n_in,
                              void* d_out, int out_size, void* d_ws, size_t ws_size,
                              hipStream_t stream)
{
  const float* input = (const float*)d_in[0];
  const float* filt  = (const float*)d_in[1];
  const float* prior = (const float*)d_in[3];
  float* out = (float*)d_out;

  char* ws = (char*)d_ws;
  u64*      packed  = (u64*)(ws);                    // 4,194,304
  float*    u       = (float*)(ws + 4194304);        // 2,097,152
  float*    smax    = (float*)(ws + 6291456);
  int*      sidx    = (int*)  (ws + 6292480);
  float*    umax    = (float*)(ws + 6293504);
  int*      pxy     = (int*)  (ws + 6294528);
  u32*      mmax    = (u32*)  (ws + 6294592);
  u32*      ncand   = (u32*)  (ws + 6294624);
  ushort_t* afh     = (ushort_t*)(ws + 6294656);     // 135168
  ushort_t* afl     = (ushort_t*)(ws + 6429824);     // 135168
  ushort_t* acolh   = (ushort_t*)(ws + 6564992);     // 4096
  float*    fcorner = (float*)(ws + 6569088);        // 8192
  float*    priorR  = (float*)(ws + 6577280);        // 8192
  u32*      cand    = (u32*)  (ws + 6585472);        // 262144 -> 6,847,616

  prep_kernel<<<64, 256, 0, stream>>>(filt, prior, afh, afl, acolh, fcorner, priorR);
  init_kernel<<<2048, 256, 0, stream>>>(packed, u, pxy, mmax, ncand);
  conv_mfma<<<dim3(32, NB), 512, 0, stream>>>(input, afh, afl, acolh, fcorner, priorR, packed);
  bmax_kernel<<<dim3(32, NB), 256, 0, stream>>>(packed, mmax);
  collect_kernel<<<dim3(32, NB), 256, 0, stream>>>(packed, mmax, ncand, cand);
  rerank_kernel<<<1024, 64, 0, stream>>>(input, filt, prior, ncand, cand, packed);
  for (int t = 0; t < 10; ++t){
    scan_kernel<<<dim3(32, NB), 256, 0, stream>>>(packed, u, pxy, smax, sidx, umax);
    final_kernel<<<NB, 64, 0, stream>>>(packed, prior, smax, sidx, umax, pxy, out, t);
  }
}